// Round 19
// baseline (1024.624 us; speedup 1.0000x reference)
//
#include <hip/hip_runtime.h>
#include <type_traits>

// ---------------------------------------------------------------------------
// CSAAttention — round 19 = round 18 + SOFTWARE-PIPELINED dot/topk:
//   dot(g+1) and topk(g) are independent -> co-dispatch them in one
//   heterogeneous launch with double-buffered dot planes (G=4, L3-resident).
//   All kernel bodies bit-identical to R18 -> absmax must stay 0.00390625.
//   Fallback (small ws): R18 sequential loop.
// ---------------------------------------------------------------------------

#define DEVI __device__ __forceinline__

constexpr int Tn = 1024;
constexpr int Cn = 1024;
constexpr int Hn = 16;

typedef short bf16x8 __attribute__((ext_vector_type(8)));
typedef float f32x4 __attribute__((ext_vector_type(4)));
typedef double f64x4 __attribute__((ext_vector_type(4)));

DEVI int wsumi(int v)   { for (int m = 1; m < 64; m <<= 1) v += __shfl_xor(v, m); return v; }
DEVI int wmini(int v)   { for (int m = 1; m < 64; m <<= 1) { int o = __shfl_xor(v, m); v = o < v ? o : v; } return v; }
DEVI float wfmax(float v){ for (int m = 1; m < 64; m <<= 1) v = fmaxf(v, __shfl_xor(v, m)); return v; }
DEVI float wfsum(float v){ for (int m = 1; m < 64; m <<= 1) v += __shfl_xor(v, m); return v; }

DEVI unsigned long long mapd(double x) {  // monotone fp64 -> uint64
  unsigned long long b = (unsigned long long)__double_as_longlong(x);
  return (b >> 63) ? ~b : (b | 0x8000000000000000ull);
}

DEVI unsigned short f2bf_rne(float x) {
  unsigned u = __float_as_uint(x);
  u += 0x7fffu + ((u >> 16) & 1u);
  return (unsigned short)(u >> 16);
}
struct BfPair { short hi, lo; };
DEVI BfPair split2(float x) {
  unsigned short h = f2bf_rne(x);
  float hf = __uint_as_float(((unsigned)h) << 16);
  BfPair r;
  r.hi = (short)h;
  r.lo = (short)f2bf_rne(x - hf);
  return r;
}

// ---------------------------------------------------------------------------
// f64-MFMA GEMM BODY (R16/R18 verbatim logic). Tile 64x64, BK=32, dbuf LDS.
// Probed layout (R12-validated), scalar fp64 fallback. Bit-identical chains.
// ---------------------------------------------------------------------------
template <typename OUTT, bool BTRANS, int BIASMODE>
DEVI void f64_body(float* AsB, float* BsB,
    const float* Ab, const float* Bb, const float* bias, OUTT* Cb,
    int Kd, int lda, int ldb, int ldc, int m0, int n0)
{
  const int tid = threadIdx.x;
  const int lane = tid & 63, w = tid >> 6;
  const int wr = w >> 1, wc = w & 1;
  const int l15 = lane & 15, l4 = lane >> 4;

  f64x4 zz = {0.0, 0.0, 0.0, 0.0};
  f64x4 p1 = __builtin_amdgcn_mfma_f64_16x16x4f64(1.0, (double)l15, zz, 0, 0, 0);
  f64x4 p2 = __builtin_amdgcn_mfma_f64_16x16x4f64((double)l15, 1.0, zz, 0, 0, 0);
  int a1 = 1, b1 = 1, c1 = 1, a2 = 1, b2 = 1, c2 = 1;
#pragma unroll
  for (int rr = 0; rr < 4; ++rr) {
    a1 &= (p1[rr] == 4.0 * l15);
    b1 &= (p1[rr] == 4.0 * (l4 * 4 + rr));
    c1 &= (p1[rr] == 4.0 * (l4 + 4 * rr));
    a2 &= (p2[rr] == 4.0 * (l4 * 4 + rr));
    b2 &= (p2[rr] == 4.0 * (l4 + 4 * rr));
    c2 &= (p2[rr] == 4.0 * l15);
  }
  a1 = __all(a1); b1 = __all(b1); c1 = __all(c1);
  a2 = __all(a2); b2 = __all(b2); c2 = __all(c2);
  int dmap = 0, useM = 1;
  if      (a1 && a2) dmap = 0;
  else if (a1 && b2) dmap = 1;
  else if (b1 && c2) dmap = 2;
  else if (c1 && c2) dmap = 3;
  else useM = 0;

  f64x4 acc[2][2];
#pragma unroll
  for (int i = 0; i < 2; ++i)
#pragma unroll
    for (int j = 0; j < 2; ++j) acc[i][j] = (f64x4){0.0, 0.0, 0.0, 0.0};

  const int sm = tid >> 2, skf = tid & 3;
  const int bkl = tid >> 4, bnf = tid & 15;

  const int nT = Kd >> 5;
  float4 a0_, a1_, b0_, b1_;

  auto LOADT = [&](int k0) {
    a0_ = *(const float4*)(Ab + (size_t)(m0 + sm) * lda + k0 + 4 * skf);
    a1_ = *(const float4*)(Ab + (size_t)(m0 + sm) * lda + k0 + 16 + 4 * skf);
    if (BTRANS) {
      b0_ = *(const float4*)(Bb + (size_t)(n0 + sm) * ldb + k0 + 4 * skf);
      b1_ = *(const float4*)(Bb + (size_t)(n0 + sm) * ldb + k0 + 16 + 4 * skf);
    } else {
      b0_ = *(const float4*)(Bb + (size_t)(k0 + bkl) * ldb + n0 + 4 * bnf);
      b1_ = *(const float4*)(Bb + (size_t)(k0 + 16 + bkl) * ldb + n0 + 4 * bnf);
    }
  };
  auto WRITET = [&](int buf) {
    float* As = AsB + buf * 2304;
    float* Bs = BsB + buf * 2304;
    As[(4 * skf + 0) * 72 + sm] = a0_.x; As[(4 * skf + 1) * 72 + sm] = a0_.y;
    As[(4 * skf + 2) * 72 + sm] = a0_.z; As[(4 * skf + 3) * 72 + sm] = a0_.w;
    As[(16 + 4 * skf + 0) * 72 + sm] = a1_.x; As[(16 + 4 * skf + 1) * 72 + sm] = a1_.y;
    As[(16 + 4 * skf + 2) * 72 + sm] = a1_.z; As[(16 + 4 * skf + 3) * 72 + sm] = a1_.w;
    if (BTRANS) {
      Bs[(4 * skf + 0) * 72 + sm] = b0_.x; Bs[(4 * skf + 1) * 72 + sm] = b0_.y;
      Bs[(4 * skf + 2) * 72 + sm] = b0_.z; Bs[(4 * skf + 3) * 72 + sm] = b0_.w;
      Bs[(16 + 4 * skf + 0) * 72 + sm] = b1_.x; Bs[(16 + 4 * skf + 1) * 72 + sm] = b1_.y;
      Bs[(16 + 4 * skf + 2) * 72 + sm] = b1_.z; Bs[(16 + 4 * skf + 3) * 72 + sm] = b1_.w;
    } else {
      *(float4*)&Bs[bkl * 72 + 4 * bnf] = b0_;
      *(float4*)&Bs[(16 + bkl) * 72 + 4 * bnf] = b1_;
    }
  };

  LOADT(0);
  WRITET(0);
  __syncthreads();

  for (int kt = 0; kt < nT; ++kt) {
    const int cur = kt & 1;
    if (kt + 1 < nT) LOADT((kt + 1) * 32);

    const float* As = AsB + cur * 2304;
    const float* Bs = BsB + cur * 2304;
    if (useM) {
#pragma unroll
      for (int kq = 0; kq < 8; ++kq) {
        int kk = kq * 4 + l4;
        double a0  = (double)As[kk * 72 + wr * 32 + l15];
        double a1v = (double)As[kk * 72 + wr * 32 + 16 + l15];
        double b0  = (double)Bs[kk * 72 + wc * 32 + l15];
        double b1v = (double)Bs[kk * 72 + wc * 32 + 16 + l15];
        acc[0][0] = __builtin_amdgcn_mfma_f64_16x16x4f64(a0,  b0,  acc[0][0], 0, 0, 0);
        acc[0][1] = __builtin_amdgcn_mfma_f64_16x16x4f64(a0,  b1v, acc[0][1], 0, 0, 0);
        acc[1][0] = __builtin_amdgcn_mfma_f64_16x16x4f64(a1v, b0,  acc[1][0], 0, 0, 0);
        acc[1][1] = __builtin_amdgcn_mfma_f64_16x16x4f64(a1v, b1v, acc[1][1], 0, 0, 0);
      }
    } else {
#pragma unroll
      for (int k = 0; k < 32; ++k) {
        double bv0 = (double)Bs[k * 72 + wc * 32 + l15];
        double bv1 = (double)Bs[k * 72 + wc * 32 + 16 + l15];
#pragma unroll
        for (int fr = 0; fr < 2; ++fr)
#pragma unroll
          for (int rr = 0; rr < 4; ++rr) {
            double av = (double)As[k * 72 + wr * 32 + fr * 16 + l4 * 4 + rr];
            acc[fr][0][rr] += av * bv0;
            acc[fr][1][rr] += av * bv1;
          }
      }
    }

    if (kt + 1 < nT) WRITET(cur ^ 1);
    __syncthreads();
  }

#pragma unroll
  for (int fr = 0; fr < 2; ++fr)
#pragma unroll
    for (int fc = 0; fc < 2; ++fc)
#pragma unroll
      for (int rr = 0; rr < 4; ++rr) {
        int ri, ci;
        if (!useM || dmap == 0) { ri = l4 * 4 + rr; ci = l15; }
        else if (dmap == 1)     { ri = l4 + 4 * rr; ci = l15; }
        else if (dmap == 2)     { ri = l15; ci = l4 * 4 + rr; }
        else                    { ri = l15; ci = l4 + 4 * rr; }
        int row = m0 + wr * 32 + fr * 16 + ri;
        int col = n0 + wc * 32 + fc * 16 + ci;
        double v = acc[fr][fc][rr];
        if constexpr (std::is_same<OUTT, double>::value) {
          Cb[(size_t)row * ldc + col] = v;
        } else {
          float s = (float)v;
          float cb = (BIASMODE == 1) ? bias[col] : 0.f;
          float rb = (BIASMODE == 2) ? bias[row] : 0.f;
          ((float*)Cb)[(size_t)row * ldc + col] = s + cb + rb;
        }
      }
}

// ---------------------------------------------------------------------------
// bf16-split value-path GEMM BODY (R18 verbatim; bit-identical to R9).
// ---------------------------------------------------------------------------
template <bool BTRANS, int BIASMODE>
DEVI void bf16_body(short* AhB, short* AlB, short* BhB, short* BlB,
    const float* A, const float* Bz, const float* bias, float* Cz,
    int Kd, int lda, int ldb, int ldc, int m0, int n0)
{
  const int tid = threadIdx.x;
  const int lane = tid & 63, w = tid >> 6;
  const int wr = w >> 1, wc = w & 1;
  const int r16 = lane & 15, kg = lane >> 4;

  f32x4 acc[2][2];
#pragma unroll
  for (int i = 0; i < 2; ++i)
#pragma unroll
    for (int j = 0; j < 2; ++j) acc[i][j] = (f32x4){0.f, 0.f, 0.f, 0.f};

  const int row = tid >> 2, kseg = tid & 3;
  const int gcol = tid & 63, gks = tid >> 6;

  const int nT = Kd >> 5;
  float4 pa0, pa1, pb0, pb1;
  float gb[8];

  auto LOADT = [&](int k0) {
    pa0 = *(const float4*)(A + (size_t)(m0 + row) * lda + k0 + kseg * 8);
    pa1 = *(const float4*)(A + (size_t)(m0 + row) * lda + k0 + kseg * 8 + 4);
    if (BTRANS) {
      pb0 = *(const float4*)(Bz + (size_t)(n0 + row) * ldb + k0 + kseg * 8);
      pb1 = *(const float4*)(Bz + (size_t)(n0 + row) * ldb + k0 + kseg * 8 + 4);
    } else {
#pragma unroll
      for (int j = 0; j < 8; ++j)
        gb[j] = Bz[(size_t)(k0 + gks * 8 + j) * ldb + n0 + gcol];
    }
  };
  auto WRITET = [&](int buf) {
    {
      BfPair q0 = split2(pa0.x), q1 = split2(pa0.y), q2 = split2(pa0.z), q3 = split2(pa0.w);
      BfPair q4 = split2(pa1.x), q5 = split2(pa1.y), q6 = split2(pa1.z), q7 = split2(pa1.w);
      bf16x8 h = {q0.hi, q1.hi, q2.hi, q3.hi, q4.hi, q5.hi, q6.hi, q7.hi};
      bf16x8 l = {q0.lo, q1.lo, q2.lo, q3.lo, q4.lo, q5.lo, q6.lo, q7.lo};
      int idx = (kseg * 64 + row) * 8;
      *(bf16x8*)&AhB[buf * 2048 + idx] = h;
      *(bf16x8*)&AlB[buf * 2048 + idx] = l;
    }
    if (BTRANS) {
      BfPair q0 = split2(pb0.x), q1 = split2(pb0.y), q2 = split2(pb0.z), q3 = split2(pb0.w);
      BfPair q4 = split2(pb1.x), q5 = split2(pb1.y), q6 = split2(pb1.z), q7 = split2(pb1.w);
      bf16x8 h = {q0.hi, q1.hi, q2.hi, q3.hi, q4.hi, q5.hi, q6.hi, q7.hi};
      bf16x8 l = {q0.lo, q1.lo, q2.lo, q3.lo, q4.lo, q5.lo, q6.lo, q7.lo};
      int idx = (kseg * 64 + row) * 8;
      *(bf16x8*)&BhB[buf * 2048 + idx] = h;
      *(bf16x8*)&BlB[buf * 2048 + idx] = l;
    } else {
      short hv[8], lv[8];
#pragma unroll
      for (int j = 0; j < 8; ++j) {
        BfPair p = split2(gb[j]);
        hv[j] = p.hi; lv[j] = p.lo;
      }
      bf16x8 h = {hv[0], hv[1], hv[2], hv[3], hv[4], hv[5], hv[6], hv[7]};
      bf16x8 l = {lv[0], lv[1], lv[2], lv[3], lv[4], lv[5], lv[6], lv[7]};
      int idx = (gks * 64 + gcol) * 8;
      *(bf16x8*)&BhB[buf * 2048 + idx] = h;
      *(bf16x8*)&BlB[buf * 2048 + idx] = l;
    }
  };

  LOADT(0);
  WRITET(0);
  __syncthreads();

  for (int kt = 0; kt < nT; ++kt) {
    const int cur = kt & 1;
    if (kt + 1 < nT) LOADT((kt + 1) * 32);

    bf16x8 ah[2], al[2], bh[2], bl[2];
#pragma unroll
    for (int f = 0; f < 2; ++f) {
      int ia = (kg * 64 + wr * 32 + f * 16 + r16) * 8;
      int ib = (kg * 64 + wc * 32 + f * 16 + r16) * 8;
      ah[f] = *(const bf16x8*)&AhB[cur * 2048 + ia];
      al[f] = *(const bf16x8*)&AlB[cur * 2048 + ia];
      bh[f] = *(const bf16x8*)&BhB[cur * 2048 + ib];
      bl[f] = *(const bf16x8*)&BlB[cur * 2048 + ib];
    }
#pragma unroll
    for (int fr = 0; fr < 2; ++fr)
#pragma unroll
      for (int fc = 0; fc < 2; ++fc) {
        f32x4 c = acc[fr][fc];
        c = __builtin_amdgcn_mfma_f32_16x16x32_bf16(al[fr], bh[fc], c, 0, 0, 0);
        c = __builtin_amdgcn_mfma_f32_16x16x32_bf16(ah[fr], bl[fc], c, 0, 0, 0);
        c = __builtin_amdgcn_mfma_f32_16x16x32_bf16(ah[fr], bh[fc], c, 0, 0, 0);
        acc[fr][fc] = c;
      }

    if (kt + 1 < nT) WRITET(cur ^ 1);
    __syncthreads();
  }

#pragma unroll
  for (int fr = 0; fr < 2; ++fr)
#pragma unroll
    for (int fc = 0; fc < 2; ++fc) {
      int col = n0 + wc * 32 + fc * 16 + r16;
      float cb = (BIASMODE == 1) ? bias[col] : 0.f;
#pragma unroll
      for (int rr = 0; rr < 4; ++rr) {
        int rw = m0 + wr * 32 + fr * 16 + kg * 4 + rr;
        float rb = (BIASMODE == 2) ? bias[rw] : 0.f;
        Cz[(size_t)rw * ldc + col] = acc[fr][fc][rr] + cb + rb;
      }
    }
}

// ---------------------------------------------------------------------------
// Top-64 + softmax + PV BODY (R5-validated algorithm, refactored).
// flat in [0, 256*Gslots): slot g = flat>>8, t = (flat&255)*4 + wv.
// ---------------------------------------------------------------------------
DEVI void topk_body(const double* __restrict__ dotb, const double* __restrict__ kn,
                    const float* __restrict__ Vc, float* __restrict__ attnout,
                    int flat, int group_base, int* sCp, float* sDp)
{
  const int lane = threadIdx.x & 63, wv = threadIdx.x >> 6;
  const int g = flat >> 8;
  const int t = (flat & 255) * 4 + wv;
  const int pair = group_base + g;
  const int bb = pair >> 4, hh = pair & 15;

  const double* drow = dotb + ((size_t)g * Tn + t) * (size_t)Cn;
  const double* knr  = kn + ((size_t)(bb * Hn + hh)) * Cn;
  int* sC = sCp + wv * 64;
  float* sD = sDp + wv * 64;

  double dv[16];
  unsigned long long u[16];
#pragma unroll
  for (int j = 0; j < 8; ++j) {
    double2 dd = *(const double2*)(drow + j * 128 + 2 * lane);
    double2 kk = *(const double2*)(knr  + j * 128 + 2 * lane);
    dv[2 * j] = dd.x; dv[2 * j + 1] = dd.y;
    u[2 * j]     = mapd(dd.x * kk.x);
    u[2 * j + 1] = mapd(dd.y * kk.y);
  }
  unsigned hi[16];
#pragma unroll
  for (int i = 0; i < 16; ++i) hi[i] = (unsigned)(u[i] >> 32);

  unsigned TH = 0;
  for (int bit = 31; bit >= 0; --bit) {
    unsigned Tc = TH | (1u << bit);
    int c = 0;
#pragma unroll
    for (int i = 0; i < 16; ++i) c += (hi[i] >= Tc);
    if (wsumi(c) >= 64) TH = Tc;
  }
  int mhi = 0;
#pragma unroll
  for (int i = 0; i < 16; ++i) mhi += (hi[i] > TH);
  mhi = wsumi(mhi);
  const int need1 = 64 - mhi;
  unsigned TL = 0;
  for (int bit = 31; bit >= 0; --bit) {
    unsigned Tc = TL | (1u << bit);
    int c = 0;
#pragma unroll
    for (int i = 0; i < 16; ++i) c += (hi[i] == TH && (unsigned)u[i] >= Tc);
    if (wsumi(c) >= need1) TL = Tc;
  }
  const unsigned long long V64 = ((unsigned long long)TH << 32) | TL;

  int base = 0;
#pragma unroll
  for (int i = 0; i < 16; ++i) {
    const int cix = 128 * (i >> 1) + 2 * lane + (i & 1);
    bool sel = (u[i] > V64);
    unsigned long long mk = __ballot(sel);
    if (sel) {
      int r = __popcll(mk & ((1ull << lane) - 1ull));
      sC[base + r] = cix;
      sD[base + r] = (float)dv[i];
    }
    base += __popcll(mk);
  }
  const int need = 64 - base;
  unsigned taken = 0;
  for (int r = 0; r < need; ++r) {
    int mn = 0x7fffffff;
#pragma unroll
    for (int i = 0; i < 16; ++i) {
      int cix = 128 * (i >> 1) + 2 * lane + (i & 1);
      if (u[i] == V64 && !((taken >> i) & 1u)) mn = mn < cix ? mn : cix;
    }
    mn = wmini(mn);
#pragma unroll
    for (int i = 0; i < 16; ++i) {
      int cix = 128 * (i >> 1) + 2 * lane + (i & 1);
      if (u[i] == V64 && !((taken >> i) & 1u) && cix == mn) {
        taken |= 1u << i;
        sC[base + r] = mn;
        sD[base + r] = (float)dv[i];
      }
    }
  }
  __syncthreads();

  int ck = sC[lane];
  float sc = sD[lane] * 0.125f;
  float mx = wfmax(sc);
  float w = expf(sc - mx);
  float sw = wfsum(w);
  w /= sw;

  const float* Vb = Vc + (size_t)bb * ((size_t)Cn * 1024) + hh * 64 + lane;
  float acc = 0.f;
#pragma unroll 4
  for (int k = 0; k < 64; ++k) {
    int c = __shfl(ck, k);
    float wk = __shfl(w, k);
    acc = fmaf(wk, Vb[(size_t)c * 1024], acc);
  }
  attnout[((size_t)(bb * Tn + t)) * 1024 + hh * 64 + lane] = acc;
}

// ---------------------------------------------------------------------------
// Fused projections: z=0 -> Q (f64), z=1 -> K (f64), z=2 -> V (bf16).
// ---------------------------------------------------------------------------
__global__ __launch_bounds__(256) void projQKV_k(
    const float* __restrict__ x,
    const float* __restrict__ Wq, const float* __restrict__ Wk,
    const float* __restrict__ Wv,
    const float* __restrict__ bq, const float* __restrict__ bk,
    const float* __restrict__ bv,
    float* __restrict__ Q, float* __restrict__ Kf, float* __restrict__ Vf)
{
  __shared__ __align__(16) float S1[2 * 2304];
  __shared__ __align__(16) float S2[2 * 2304];
  const int m0 = blockIdx.y * 64, n0 = blockIdx.x * 64;
  if (blockIdx.z < 2) {
    const float* W = blockIdx.z ? Wk : Wq;
    const float* b = blockIdx.z ? bk : bq;
    float* C = blockIdx.z ? Kf : Q;
    f64_body<float, true, 1>(S1, S2, x, W, b, C, 1024, 1024, 1024, 1024, m0, n0);
  } else {
    bf16_body<true, 1>((short*)S1, (short*)S1 + 4096,
                       (short*)S2, (short*)S2 + 4096,
                       x, Wv, bv, Vf, 1024, 1024, 1024, 1024, m0, n0);
  }
}

// Fused compress: z=0,1 -> Kc batches (f64); z=2,3 -> Vc batches (bf16).
__global__ __launch_bounds__(256) void compKV_k(
    const float* __restrict__ Wc, const float* __restrict__ Kf,
    const float* __restrict__ Vf, const float* __restrict__ bc,
    float* __restrict__ Kc, float* __restrict__ Vc)
{
  __shared__ __align__(16) float S1[2 * 2304];
  __shared__ __align__(16) float S2[2 * 2304];
  const int m0 = blockIdx.y * 64, n0 = blockIdx.x * 64;
  const size_t M1 = (size_t)1024 * 1024;
  if (blockIdx.z < 2) {
    f64_body<float, false, 2>(S1, S2, Wc, Kf + blockIdx.z * M1, bc,
                              Kc + blockIdx.z * M1, 1024, 1024, 1024, 1024, m0, n0);
  } else {
    int zb = blockIdx.z - 2;
    bf16_body<false, 2>((short*)S1, (short*)S1 + 4096,
                        (short*)S2, (short*)S2 + 4096,
                        Wc, Vf + zb * M1, bc, Vc + zb * M1,
                        1024, 1024, 1024, 1024, m0, n0);
  }
}

// Dot planes standalone (f64 SIM): z = slot; pair = group_base + z.
__global__ __launch_bounds__(256) void dotsim_k(
    const float* __restrict__ Q, const float* __restrict__ Kc,
    double* __restrict__ dotp, int group_base)
{
  __shared__ __align__(16) float S1[2 * 2304];
  __shared__ __align__(16) float S2[2 * 2304];
  const int m0 = blockIdx.y * 64, n0 = blockIdx.x * 64;
  int pair = group_base + (int)blockIdx.z;
  int bb = pair >> 4, hh = pair & 15;
  const float* Ab = Q + ((size_t)bb * Tn) * 1024 + (size_t)hh * 64;
  const float* Bb = Kc + ((size_t)bb * Cn) * 1024 + (size_t)hh * 64;
  double* Cb = dotp + (size_t)blockIdx.z * Tn * Cn;
  f64_body<double, true, 0>(S1, S2, Ab, Bb, nullptr, Cb, 64, 1024, 1024, 1024, m0, n0);
}

// Topk standalone: grid 256*G, slot = blockIdx>>8.
__global__ __launch_bounds__(256) void topk_attn_k(
    const double* __restrict__ dotb, const double* __restrict__ kn,
    const float* __restrict__ Vc, float* __restrict__ attnout, int group_base)
{
  __shared__ int sC[4 * 64];
  __shared__ float sD[4 * 64];
  topk_body(dotb, kn, Vc, attnout, (int)blockIdx.x, group_base, sC, sD);
}

// ---------------------------------------------------------------------------
// PIPELINED dot/topk: blocks [0,1024) = dots for group gnext into dnext
// (4 pairs x 256 tiles); blocks [1024,2048) = topk for group gcur from dcur.
// Independent work -> co-scheduled, hiding topk's HBM phase under dot MFMA.
// ---------------------------------------------------------------------------
__global__ __launch_bounds__(256) void pipe_k(
    const float* __restrict__ Q, const float* __restrict__ Kc,
    const double* __restrict__ kn, const float* __restrict__ Vc,
    float* __restrict__ at, const double* __restrict__ dcur,
    double* __restrict__ dnext, int gcur_base, int gnext_base)
{
  __shared__ __align__(16) float S1[2 * 2304];
  __shared__ __align__(16) float S2[2 * 2304];
  const int flat = (int)blockIdx.x;
  if (flat < 1024) {          // dot part
    int z = flat >> 8, r = flat & 255;
    int m0 = (r >> 4) * 64, n0 = (r & 15) * 64;
    int pair = gnext_base + z;
    int bb = pair >> 4, hh = pair & 15;
    const float* Ab = Q + ((size_t)bb * Tn) * 1024 + (size_t)hh * 64;
    const float* Bb = Kc + ((size_t)bb * Cn) * 1024 + (size_t)hh * 64;
    double* Cb = dnext + (size_t)z * Tn * Cn;
    f64_body<double, true, 0>(S1, S2, Ab, Bb, nullptr, Cb, 64, 1024, 1024, 1024, m0, n0);
  } else {                    // topk part
    topk_body(dcur, kn, Vc, at, flat - 1024, gcur_base, (int*)S1, (float*)S2);
  }
}

// kn[b*16+h][c] = 1 / max(||Kc[b, c, h*64 : +64]||, 1e-12)   (fp64)
__global__ __launch_bounds__(256) void kn_k2(const float* __restrict__ Kc,
                                             double* __restrict__ kn)
{
  int idx = (int)blockIdx.x * 256 + (int)threadIdx.x;
  int c = idx & 1023;
  int p = idx >> 10;
  int b = p >> 4, h = p & 15;
  const float* row = Kc + ((size_t)(b * 1024 + c)) * 1024 + h * 64;
  double s = 0.0;
  for (int d = 0; d < 64; ++d) { double v = (double)row[d]; s += v * v; }
  kn[(size_t)p * 1024 + c] = 1.0 / fmax(sqrt(s), 1e-12);
}

// Output projection (bf16, standalone).
__global__ __launch_bounds__(256) void wo_k(
    const float* __restrict__ at, const float* __restrict__ Wo,
    const float* __restrict__ bo, float* __restrict__ out)
{
  __shared__ __align__(16) float S1[2 * 2304];
  __shared__ __align__(16) float S2[2 * 2304];
  const int m0 = blockIdx.y * 64, n0 = blockIdx.x * 64;
  bf16_body<true, 1>((short*)S1, (short*)S1 + 4096,
                     (short*)S2, (short*)S2 + 4096,
                     at, Wo, bo, out, 1024, 1024, 1024, 1024, m0, n0);
}

// ---------------------------------------------------------------------------
extern "C" void kernel_launch(void* const* d_in, const int* in_sizes, int n_in,
                              void* d_out, int out_size, void* d_ws, size_t ws_size,
                              hipStream_t stream)
{
  const float* x  = (const float*)d_in[0];
  const float* Wq = (const float*)d_in[1];
  const float* bq = (const float*)d_in[2];
  const float* Wk = (const float*)d_in[3];
  const float* bk = (const float*)d_in[4];
  const float* Wv = (const float*)d_in[5];
  const float* bv = (const float*)d_in[6];
  const float* Wo = (const float*)d_in[7];
  const float* bo = (const float*)d_in[8];
  const float* Wc = (const float*)d_in[9];
  const float* bc = (const float*)d_in[10];
  float* out = (float*)d_out;

  const size_t NE = (size_t)2048 * 1024;
  float* Q   = (float*)d_ws;
  float* Kf  = Q + NE;
  float* Vf  = Kf + NE;
  float* Kc  = Vf + NE;
  float* Vc  = Kc + NE;
  float* at  = Vc + NE;
  double* kn = (double*)(at + NE);
  double* tail = kn + 32768;

  const size_t fixedB = 6 * NE * 4 + 32768 * 8;
  const size_t dotPairB = (size_t)Tn * Cn * 8;   // 8 MiB per (b,h) pair
  if (ws_size < fixedB) return;

  dim3 blk(256, 1, 1);

  // Fused Q/K (f64) + V (bf16) projections
  projQKV_k<<<dim3(16, 32, 3), blk, 0, stream>>>(
      x, Wq, Wk, Wv, bq, bk, bv, Q, Kf, Vf);

  // Fused Kc (f64) + Vc (bf16) compress
  compKV_k<<<dim3(16, 16, 4), blk, 0, stream>>>(Wc, Kf, Vf, bc, Kc, Vc);

  kn_k2<<<dim3(128), blk, 0, stream>>>(Kc, kn);

  size_t rem = ws_size - fixedB;
  const size_t planeElems = (size_t)4 * Tn * Cn;   // 4-pair plane

  if (rem >= 8 * dotPairB) {
    // Pipelined: dot(0); 7x [topk(g) || dot(g+1)]; topk(7). Buffers ping-pong.
    double* bufs[2] = { tail, tail + planeElems };
    dotsim_k<<<dim3(16, 16, 4), blk, 0, stream>>>(Q, Kc, bufs[0], 0);
    for (int g = 0; g < 7; ++g) {
      pipe_k<<<dim3(2048), blk, 0, stream>>>(
          Q, Kc, kn, Vc, at, bufs[g & 1], bufs[(g + 1) & 1],
          g * 4, (g + 1) * 4);
    }
    topk_attn_k<<<dim3(1024), blk, 0, stream>>>(bufs[1], kn, Vc, at, 28);
  } else {
    // Fallback: sequential (G tiered; dotp in dead Kf+Vf if needed)
    double* dotp; int G;
    if      (rem >= 4 * dotPairB) { G = 4; dotp = tail; }
    else if (rem >= 2 * dotPairB) { G = 2; dotp = tail; }
    else { G = 2; dotp = (double*)Kf; }
    for (int gb = 0; gb < 32; gb += G) {
      dotsim_k<<<dim3(16, 16, G), blk, 0, stream>>>(Q, Kc, dotp, gb);
      topk_attn_k<<<dim3(256 * G), blk, 0, stream>>>(dotp, kn, Vc, at, gb);
    }
  }

  // Output projection (bf16)
  wo_k<<<dim3(16, 32, 1), blk, 0, stream>>>(at, Wo, bo, out);
}

// Round 20
// 811.033 us; speedup vs baseline: 1.2634x; 1.2634x over previous
//
#include <hip/hip_runtime.h>
#include <type_traits>

// ---------------------------------------------------------------------------
// CSAAttention — round 20 = round 18 VERBATIM (best measured: 809us).
//   R19's dot/topk pipelining reverted (LDS-asymmetric fusion: topk blocks
//   forced to 36KB LDS -> occupancy collapse, +215us).
//   Structure: fused Q/K(f64)+V(bf16) projections, fused Kc(f64)+Vc(bf16)
//   compress, f64-MFMA dot planes (probed layout), exact radix top-64 +
//   softmax + PV, bf16-split Wo. Selection path bit-frozen since R4.
// ---------------------------------------------------------------------------

#define DEVI __device__ __forceinline__

constexpr int Tn = 1024;
constexpr int Cn = 1024;
constexpr int Hn = 16;

typedef short bf16x8 __attribute__((ext_vector_type(8)));
typedef float f32x4 __attribute__((ext_vector_type(4)));
typedef double f64x4 __attribute__((ext_vector_type(4)));

DEVI int wsumi(int v)   { for (int m = 1; m < 64; m <<= 1) v += __shfl_xor(v, m); return v; }
DEVI int wmini(int v)   { for (int m = 1; m < 64; m <<= 1) { int o = __shfl_xor(v, m); v = o < v ? o : v; } return v; }
DEVI float wfmax(float v){ for (int m = 1; m < 64; m <<= 1) v = fmaxf(v, __shfl_xor(v, m)); return v; }
DEVI float wfsum(float v){ for (int m = 1; m < 64; m <<= 1) v += __shfl_xor(v, m); return v; }

DEVI unsigned long long mapd(double x) {  // monotone fp64 -> uint64
  unsigned long long b = (unsigned long long)__double_as_longlong(x);
  return (b >> 63) ? ~b : (b | 0x8000000000000000ull);
}

DEVI unsigned short f2bf_rne(float x) {
  unsigned u = __float_as_uint(x);
  u += 0x7fffu + ((u >> 16) & 1u);
  return (unsigned short)(u >> 16);
}
struct BfPair { short hi, lo; };
DEVI BfPair split2(float x) {
  unsigned short h = f2bf_rne(x);
  float hf = __uint_as_float(((unsigned)h) << 16);
  BfPair r;
  r.hi = (short)h;
  r.lo = (short)f2bf_rne(x - hf);
  return r;
}

// ---------------------------------------------------------------------------
// f64-MFMA GEMM BODY. Tile 64x64, BK=32, double-buffered LDS.
// Probed layout (R12-validated), scalar fp64 fallback.
// Per-accumulator ascending-k chains -> bit-identical to R12-R18.
// ---------------------------------------------------------------------------
template <typename OUTT, bool BTRANS, int BIASMODE>
DEVI void f64_body(float* AsB, float* BsB,
    const float* Ab, const float* Bb, const float* bias, OUTT* Cb,
    int Kd, int lda, int ldb, int ldc, int m0, int n0)
{
  const int tid = threadIdx.x;
  const int lane = tid & 63, w = tid >> 6;
  const int wr = w >> 1, wc = w & 1;
  const int l15 = lane & 15, l4 = lane >> 4;

  f64x4 zz = {0.0, 0.0, 0.0, 0.0};
  f64x4 p1 = __builtin_amdgcn_mfma_f64_16x16x4f64(1.0, (double)l15, zz, 0, 0, 0);
  f64x4 p2 = __builtin_amdgcn_mfma_f64_16x16x4f64((double)l15, 1.0, zz, 0, 0, 0);
  int a1 = 1, b1 = 1, c1 = 1, a2 = 1, b2 = 1, c2 = 1;
#pragma unroll
  for (int rr = 0; rr < 4; ++rr) {
    a1 &= (p1[rr] == 4.0 * l15);
    b1 &= (p1[rr] == 4.0 * (l4 * 4 + rr));
    c1 &= (p1[rr] == 4.0 * (l4 + 4 * rr));
    a2 &= (p2[rr] == 4.0 * (l4 * 4 + rr));
    b2 &= (p2[rr] == 4.0 * (l4 + 4 * rr));
    c2 &= (p2[rr] == 4.0 * l15);
  }
  a1 = __all(a1); b1 = __all(b1); c1 = __all(c1);
  a2 = __all(a2); b2 = __all(b2); c2 = __all(c2);
  int dmap = 0, useM = 1;
  if      (a1 && a2) dmap = 0;
  else if (a1 && b2) dmap = 1;
  else if (b1 && c2) dmap = 2;
  else if (c1 && c2) dmap = 3;
  else useM = 0;

  f64x4 acc[2][2];
#pragma unroll
  for (int i = 0; i < 2; ++i)
#pragma unroll
    for (int j = 0; j < 2; ++j) acc[i][j] = (f64x4){0.0, 0.0, 0.0, 0.0};

  const int sm = tid >> 2, skf = tid & 3;           // A / B-trans rows
  const int bkl = tid >> 4, bnf = tid & 15;         // B non-trans

  const int nT = Kd >> 5;
  float4 a0_, a1_, b0_, b1_;

  auto LOADT = [&](int k0) {
    a0_ = *(const float4*)(Ab + (size_t)(m0 + sm) * lda + k0 + 4 * skf);
    a1_ = *(const float4*)(Ab + (size_t)(m0 + sm) * lda + k0 + 16 + 4 * skf);
    if (BTRANS) {
      b0_ = *(const float4*)(Bb + (size_t)(n0 + sm) * ldb + k0 + 4 * skf);
      b1_ = *(const float4*)(Bb + (size_t)(n0 + sm) * ldb + k0 + 16 + 4 * skf);
    } else {
      b0_ = *(const float4*)(Bb + (size_t)(k0 + bkl) * ldb + n0 + 4 * bnf);
      b1_ = *(const float4*)(Bb + (size_t)(k0 + 16 + bkl) * ldb + n0 + 4 * bnf);
    }
  };
  auto WRITET = [&](int buf) {
    float* As = AsB + buf * 2304;
    float* Bs = BsB + buf * 2304;
    As[(4 * skf + 0) * 72 + sm] = a0_.x; As[(4 * skf + 1) * 72 + sm] = a0_.y;
    As[(4 * skf + 2) * 72 + sm] = a0_.z; As[(4 * skf + 3) * 72 + sm] = a0_.w;
    As[(16 + 4 * skf + 0) * 72 + sm] = a1_.x; As[(16 + 4 * skf + 1) * 72 + sm] = a1_.y;
    As[(16 + 4 * skf + 2) * 72 + sm] = a1_.z; As[(16 + 4 * skf + 3) * 72 + sm] = a1_.w;
    if (BTRANS) {
      Bs[(4 * skf + 0) * 72 + sm] = b0_.x; Bs[(4 * skf + 1) * 72 + sm] = b0_.y;
      Bs[(4 * skf + 2) * 72 + sm] = b0_.z; Bs[(4 * skf + 3) * 72 + sm] = b0_.w;
      Bs[(16 + 4 * skf + 0) * 72 + sm] = b1_.x; Bs[(16 + 4 * skf + 1) * 72 + sm] = b1_.y;
      Bs[(16 + 4 * skf + 2) * 72 + sm] = b1_.z; Bs[(16 + 4 * skf + 3) * 72 + sm] = b1_.w;
    } else {
      *(float4*)&Bs[bkl * 72 + 4 * bnf] = b0_;
      *(float4*)&Bs[(16 + bkl) * 72 + 4 * bnf] = b1_;
    }
  };

  LOADT(0);
  WRITET(0);
  __syncthreads();

  for (int kt = 0; kt < nT; ++kt) {
    const int cur = kt & 1;
    if (kt + 1 < nT) LOADT((kt + 1) * 32);

    const float* As = AsB + cur * 2304;
    const float* Bs = BsB + cur * 2304;
    if (useM) {
#pragma unroll
      for (int kq = 0; kq < 8; ++kq) {
        int kk = kq * 4 + l4;
        double a0  = (double)As[kk * 72 + wr * 32 + l15];
        double a1v = (double)As[kk * 72 + wr * 32 + 16 + l15];
        double b0  = (double)Bs[kk * 72 + wc * 32 + l15];
        double b1v = (double)Bs[kk * 72 + wc * 32 + 16 + l15];
        acc[0][0] = __builtin_amdgcn_mfma_f64_16x16x4f64(a0,  b0,  acc[0][0], 0, 0, 0);
        acc[0][1] = __builtin_amdgcn_mfma_f64_16x16x4f64(a0,  b1v, acc[0][1], 0, 0, 0);
        acc[1][0] = __builtin_amdgcn_mfma_f64_16x16x4f64(a1v, b0,  acc[1][0], 0, 0, 0);
        acc[1][1] = __builtin_amdgcn_mfma_f64_16x16x4f64(a1v, b1v, acc[1][1], 0, 0, 0);
      }
    } else {
#pragma unroll
      for (int k = 0; k < 32; ++k) {
        double bv0 = (double)Bs[k * 72 + wc * 32 + l15];
        double bv1 = (double)Bs[k * 72 + wc * 32 + 16 + l15];
#pragma unroll
        for (int fr = 0; fr < 2; ++fr)
#pragma unroll
          for (int rr = 0; rr < 4; ++rr) {
            double av = (double)As[k * 72 + wr * 32 + fr * 16 + l4 * 4 + rr];
            acc[fr][0][rr] += av * bv0;
            acc[fr][1][rr] += av * bv1;
          }
      }
    }

    if (kt + 1 < nT) WRITET(cur ^ 1);
    __syncthreads();
  }

#pragma unroll
  for (int fr = 0; fr < 2; ++fr)
#pragma unroll
    for (int fc = 0; fc < 2; ++fc)
#pragma unroll
      for (int rr = 0; rr < 4; ++rr) {
        int ri, ci;
        if (!useM || dmap == 0) { ri = l4 * 4 + rr; ci = l15; }
        else if (dmap == 1)     { ri = l4 + 4 * rr; ci = l15; }
        else if (dmap == 2)     { ri = l15; ci = l4 * 4 + rr; }
        else                    { ri = l15; ci = l4 + 4 * rr; }
        int row = m0 + wr * 32 + fr * 16 + ri;
        int col = n0 + wc * 32 + fc * 16 + ci;
        double v = acc[fr][fc][rr];
        if constexpr (std::is_same<OUTT, double>::value) {
          Cb[(size_t)row * ldc + col] = v;
        } else {
          float s = (float)v;
          float cb = (BIASMODE == 1) ? bias[col] : 0.f;
          float rb = (BIASMODE == 2) ? bias[row] : 0.f;
          ((float*)Cb)[(size_t)row * ldc + col] = s + cb + rb;
        }
      }
}

// ---------------------------------------------------------------------------
// bf16-split value-path GEMM BODY (bit-identical to R9).
// ---------------------------------------------------------------------------
template <bool BTRANS, int BIASMODE>
DEVI void bf16_body(short* AhB, short* AlB, short* BhB, short* BlB,
    const float* A, const float* Bz, const float* bias, float* Cz,
    int Kd, int lda, int ldb, int ldc, int m0, int n0)
{
  const int tid = threadIdx.x;
  const int lane = tid & 63, w = tid >> 6;
  const int wr = w >> 1, wc = w & 1;
  const int r16 = lane & 15, kg = lane >> 4;

  f32x4 acc[2][2];
#pragma unroll
  for (int i = 0; i < 2; ++i)
#pragma unroll
    for (int j = 0; j < 2; ++j) acc[i][j] = (f32x4){0.f, 0.f, 0.f, 0.f};

  const int row = tid >> 2, kseg = tid & 3;
  const int gcol = tid & 63, gks = tid >> 6;

  const int nT = Kd >> 5;
  float4 pa0, pa1, pb0, pb1;
  float gb[8];

  auto LOADT = [&](int k0) {
    pa0 = *(const float4*)(A + (size_t)(m0 + row) * lda + k0 + kseg * 8);
    pa1 = *(const float4*)(A + (size_t)(m0 + row) * lda + k0 + kseg * 8 + 4);
    if (BTRANS) {
      pb0 = *(const float4*)(Bz + (size_t)(n0 + row) * ldb + k0 + kseg * 8);
      pb1 = *(const float4*)(Bz + (size_t)(n0 + row) * ldb + k0 + kseg * 8 + 4);
    } else {
#pragma unroll
      for (int j = 0; j < 8; ++j)
        gb[j] = Bz[(size_t)(k0 + gks * 8 + j) * ldb + n0 + gcol];
    }
  };
  auto WRITET = [&](int buf) {
    {
      BfPair q0 = split2(pa0.x), q1 = split2(pa0.y), q2 = split2(pa0.z), q3 = split2(pa0.w);
      BfPair q4 = split2(pa1.x), q5 = split2(pa1.y), q6 = split2(pa1.z), q7 = split2(pa1.w);
      bf16x8 h = {q0.hi, q1.hi, q2.hi, q3.hi, q4.hi, q5.hi, q6.hi, q7.hi};
      bf16x8 l = {q0.lo, q1.lo, q2.lo, q3.lo, q4.lo, q5.lo, q6.lo, q7.lo};
      int idx = (kseg * 64 + row) * 8;
      *(bf16x8*)&AhB[buf * 2048 + idx] = h;
      *(bf16x8*)&AlB[buf * 2048 + idx] = l;
    }
    if (BTRANS) {
      BfPair q0 = split2(pb0.x), q1 = split2(pb0.y), q2 = split2(pb0.z), q3 = split2(pb0.w);
      BfPair q4 = split2(pb1.x), q5 = split2(pb1.y), q6 = split2(pb1.z), q7 = split2(pb1.w);
      bf16x8 h = {q0.hi, q1.hi, q2.hi, q3.hi, q4.hi, q5.hi, q6.hi, q7.hi};
      bf16x8 l = {q0.lo, q1.lo, q2.lo, q3.lo, q4.lo, q5.lo, q6.lo, q7.lo};
      int idx = (kseg * 64 + row) * 8;
      *(bf16x8*)&BhB[buf * 2048 + idx] = h;
      *(bf16x8*)&BlB[buf * 2048 + idx] = l;
    } else {
      short hv[8], lv[8];
#pragma unroll
      for (int j = 0; j < 8; ++j) {
        BfPair p = split2(gb[j]);
        hv[j] = p.hi; lv[j] = p.lo;
      }
      bf16x8 h = {hv[0], hv[1], hv[2], hv[3], hv[4], hv[5], hv[6], hv[7]};
      bf16x8 l = {lv[0], lv[1], lv[2], lv[3], lv[4], lv[5], lv[6], lv[7]};
      int idx = (gks * 64 + gcol) * 8;
      *(bf16x8*)&BhB[buf * 2048 + idx] = h;
      *(bf16x8*)&BlB[buf * 2048 + idx] = l;
    }
  };

  LOADT(0);
  WRITET(0);
  __syncthreads();

  for (int kt = 0; kt < nT; ++kt) {
    const int cur = kt & 1;
    if (kt + 1 < nT) LOADT((kt + 1) * 32);

    bf16x8 ah[2], al[2], bh[2], bl[2];
#pragma unroll
    for (int f = 0; f < 2; ++f) {
      int ia = (kg * 64 + wr * 32 + f * 16 + r16) * 8;
      int ib = (kg * 64 + wc * 32 + f * 16 + r16) * 8;
      ah[f] = *(const bf16x8*)&AhB[cur * 2048 + ia];
      al[f] = *(const bf16x8*)&AlB[cur * 2048 + ia];
      bh[f] = *(const bf16x8*)&BhB[cur * 2048 + ib];
      bl[f] = *(const bf16x8*)&BlB[cur * 2048 + ib];
    }
#pragma unroll
    for (int fr = 0; fr < 2; ++fr)
#pragma unroll
      for (int fc = 0; fc < 2; ++fc) {
        f32x4 c = acc[fr][fc];
        c = __builtin_amdgcn_mfma_f32_16x16x32_bf16(al[fr], bh[fc], c, 0, 0, 0);
        c = __builtin_amdgcn_mfma_f32_16x16x32_bf16(ah[fr], bl[fc], c, 0, 0, 0);
        c = __builtin_amdgcn_mfma_f32_16x16x32_bf16(ah[fr], bh[fc], c, 0, 0, 0);
        acc[fr][fc] = c;
      }

    if (kt + 1 < nT) WRITET(cur ^ 1);
    __syncthreads();
  }

#pragma unroll
  for (int fr = 0; fr < 2; ++fr)
#pragma unroll
    for (int fc = 0; fc < 2; ++fc) {
      int col = n0 + wc * 32 + fc * 16 + r16;
      float cb = (BIASMODE == 1) ? bias[col] : 0.f;
#pragma unroll
      for (int rr = 0; rr < 4; ++rr) {
        int rw = m0 + wr * 32 + fr * 16 + kg * 4 + rr;
        float rb = (BIASMODE == 2) ? bias[rw] : 0.f;
        Cz[(size_t)rw * ldc + col] = acc[fr][fc][rr] + cb + rb;
      }
    }
}

// ---------------------------------------------------------------------------
// Fused projections: z=0 -> Q (f64), z=1 -> K (f64), z=2 -> V (bf16).
// ---------------------------------------------------------------------------
__global__ __launch_bounds__(256) void projQKV_k(
    const float* __restrict__ x,
    const float* __restrict__ Wq, const float* __restrict__ Wk,
    const float* __restrict__ Wv,
    const float* __restrict__ bq, const float* __restrict__ bk,
    const float* __restrict__ bv,
    float* __restrict__ Q, float* __restrict__ Kf, float* __restrict__ Vf)
{
  __shared__ __align__(16) float S1[2 * 2304];
  __shared__ __align__(16) float S2[2 * 2304];
  const int m0 = blockIdx.y * 64, n0 = blockIdx.x * 64;
  if (blockIdx.z < 2) {
    const float* W = blockIdx.z ? Wk : Wq;
    const float* b = blockIdx.z ? bk : bq;
    float* C = blockIdx.z ? Kf : Q;
    f64_body<float, true, 1>(S1, S2, x, W, b, C, 1024, 1024, 1024, 1024, m0, n0);
  } else {
    bf16_body<true, 1>((short*)S1, (short*)S1 + 4096,
                       (short*)S2, (short*)S2 + 4096,
                       x, Wv, bv, Vf, 1024, 1024, 1024, 1024, m0, n0);
  }
}

// Fused compress: z=0,1 -> Kc batches (f64); z=2,3 -> Vc batches (bf16).
__global__ __launch_bounds__(256) void compKV_k(
    const float* __restrict__ Wc, const float* __restrict__ Kf,
    const float* __restrict__ Vf, const float* __restrict__ bc,
    float* __restrict__ Kc, float* __restrict__ Vc)
{
  __shared__ __align__(16) float S1[2 * 2304];
  __shared__ __align__(16) float S2[2 * 2304];
  const int m0 = blockIdx.y * 64, n0 = blockIdx.x * 64;
  const size_t M1 = (size_t)1024 * 1024;
  if (blockIdx.z < 2) {
    f64_body<float, false, 2>(S1, S2, Wc, Kf + blockIdx.z * M1, bc,
                              Kc + blockIdx.z * M1, 1024, 1024, 1024, 1024, m0, n0);
  } else {
    int zb = blockIdx.z - 2;
    bf16_body<false, 2>((short*)S1, (short*)S1 + 4096,
                        (short*)S2, (short*)S2 + 4096,
                        Wc, Vf + zb * M1, bc, Vc + zb * M1,
                        1024, 1024, 1024, 1024, m0, n0);
  }
}

// Dot planes (f64 SIM): z = group slot; pair = group_base + z.
__global__ __launch_bounds__(256) void dotsim_k(
    const float* __restrict__ Q, const float* __restrict__ Kc,
    double* __restrict__ dotp, int group_base)
{
  __shared__ __align__(16) float S1[2 * 2304];
  __shared__ __align__(16) float S2[2 * 2304];
  const int m0 = blockIdx.y * 64, n0 = blockIdx.x * 64;
  int pair = group_base + (int)blockIdx.z;
  int bb = pair >> 4, hh = pair & 15;
  const float* Ab = Q + ((size_t)bb * Tn) * 1024 + (size_t)hh * 64;
  const float* Bb = Kc + ((size_t)bb * Cn) * 1024 + (size_t)hh * 64;
  double* Cb = dotp + (size_t)blockIdx.z * Tn * Cn;
  f64_body<double, true, 0>(S1, S2, Ab, Bb, nullptr, Cb, 64, 1024, 1024, 1024, m0, n0);
}

// Output projection (bf16, standalone).
__global__ __launch_bounds__(256) void wo_k(
    const float* __restrict__ at, const float* __restrict__ Wo,
    const float* __restrict__ bo, float* __restrict__ out)
{
  __shared__ __align__(16) float S1[2 * 2304];
  __shared__ __align__(16) float S2[2 * 2304];
  const int m0 = blockIdx.y * 64, n0 = blockIdx.x * 64;
  bf16_body<true, 1>((short*)S1, (short*)S1 + 4096,
                     (short*)S2, (short*)S2 + 4096,
                     at, Wo, bo, out, 1024, 1024, 1024, 1024, m0, n0);
}

// kn[b*16+h][c] = 1 / max(||Kc[b, c, h*64 : +64]||, 1e-12)   (fp64)
__global__ __launch_bounds__(256) void kn_k2(const float* __restrict__ Kc,
                                             double* __restrict__ kn)
{
  int idx = (int)blockIdx.x * 256 + (int)threadIdx.x;
  int c = idx & 1023;
  int p = idx >> 10;
  int b = p >> 4, h = p & 15;
  const float* row = Kc + ((size_t)(b * 1024 + c)) * 1024 + h * 64;
  double s = 0.0;
  for (int d = 0; d < 64; ++d) { double v = (double)row[d]; s += v * v; }
  kn[(size_t)p * 1024 + c] = 1.0 / fmax(sqrt(s), 1e-12);
}

// Fused exact top-64 + softmax + PV (bit-frozen, R5-validated).
__global__ __launch_bounds__(256) void topk_attn_k(
    const double* __restrict__ dotb, const double* __restrict__ kn,
    const float* __restrict__ Vc, float* __restrict__ attnout, int group_base)
{
  __shared__ int sC[4][64];
  __shared__ float sD[4][64];

  const int lane = threadIdx.x & 63, wv = threadIdx.x >> 6;
  const int g = (int)blockIdx.x >> 8;
  const int t = ((int)blockIdx.x & 255) * 4 + wv;
  const int pair = group_base + g;
  const int bb = pair >> 4, hh = pair & 15;

  const double* drow = dotb + ((size_t)g * Tn + t) * (size_t)Cn;
  const double* knr  = kn + ((size_t)(bb * Hn + hh)) * Cn;

  double dv[16];
  unsigned long long u[16];
#pragma unroll
  for (int j = 0; j < 8; ++j) {
    double2 dd = *(const double2*)(drow + j * 128 + 2 * lane);
    double2 kk = *(const double2*)(knr  + j * 128 + 2 * lane);
    dv[2 * j] = dd.x; dv[2 * j + 1] = dd.y;
    u[2 * j]     = mapd(dd.x * kk.x);
    u[2 * j + 1] = mapd(dd.y * kk.y);
  }
  unsigned hi[16];
#pragma unroll
  for (int i = 0; i < 16; ++i) hi[i] = (unsigned)(u[i] >> 32);

  unsigned TH = 0;
  for (int bit = 31; bit >= 0; --bit) {
    unsigned Tc = TH | (1u << bit);
    int c = 0;
#pragma unroll
    for (int i = 0; i < 16; ++i) c += (hi[i] >= Tc);
    if (wsumi(c) >= 64) TH = Tc;
  }
  int mhi = 0;
#pragma unroll
  for (int i = 0; i < 16; ++i) mhi += (hi[i] > TH);
  mhi = wsumi(mhi);
  const int need1 = 64 - mhi;
  unsigned TL = 0;
  for (int bit = 31; bit >= 0; --bit) {
    unsigned Tc = TL | (1u << bit);
    int c = 0;
#pragma unroll
    for (int i = 0; i < 16; ++i) c += (hi[i] == TH && (unsigned)u[i] >= Tc);
    if (wsumi(c) >= need1) TL = Tc;
  }
  const unsigned long long V64 = ((unsigned long long)TH << 32) | TL;

  int base = 0;
#pragma unroll
  for (int i = 0; i < 16; ++i) {
    const int cix = 128 * (i >> 1) + 2 * lane + (i & 1);
    bool sel = (u[i] > V64);
    unsigned long long mk = __ballot(sel);
    if (sel) {
      int r = __popcll(mk & ((1ull << lane) - 1ull));
      sC[wv][base + r] = cix;
      sD[wv][base + r] = (float)dv[i];
    }
    base += __popcll(mk);
  }
  const int need = 64 - base;
  unsigned taken = 0;
  for (int r = 0; r < need; ++r) {
    int mn = 0x7fffffff;
#pragma unroll
    for (int i = 0; i < 16; ++i) {
      int cix = 128 * (i >> 1) + 2 * lane + (i & 1);
      if (u[i] == V64 && !((taken >> i) & 1u)) mn = mn < cix ? mn : cix;
    }
    mn = wmini(mn);
#pragma unroll
    for (int i = 0; i < 16; ++i) {
      int cix = 128 * (i >> 1) + 2 * lane + (i & 1);
      if (u[i] == V64 && !((taken >> i) & 1u) && cix == mn) {
        taken |= 1u << i;
        sC[wv][base + r] = mn;
        sD[wv][base + r] = (float)dv[i];
      }
    }
  }
  __syncthreads();

  int ck = sC[wv][lane];
  float sc = sD[wv][lane] * 0.125f;
  float mx = wfmax(sc);
  float w = expf(sc - mx);
  float sw = wfsum(w);
  w /= sw;

  const float* Vb = Vc + (size_t)bb * ((size_t)Cn * 1024) + hh * 64 + lane;
  float acc = 0.f;
#pragma unroll 4
  for (int k = 0; k < 64; ++k) {
    int c = __shfl(ck, k);
    float wk = __shfl(w, k);
    acc = fmaf(wk, Vb[(size_t)c * 1024], acc);
  }
  attnout[((size_t)(bb * Tn + t)) * 1024 + hh * 64 + lane] = acc;
}

// ---------------------------------------------------------------------------
extern "C" void kernel_launch(void* const* d_in, const int* in_sizes, int n_in,
                              void* d_out, int out_size, void* d_ws, size_t ws_size,
                              hipStream_t stream)
{
  const float* x  = (const float*)d_in[0];
  const float* Wq = (const float*)d_in[1];
  const float* bq = (const float*)d_in[2];
  const float* Wk = (const float*)d_in[3];
  const float* bk = (const float*)d_in[4];
  const float* Wv = (const float*)d_in[5];
  const float* bv = (const float*)d_in[6];
  const float* Wo = (const float*)d_in[7];
  const float* bo = (const float*)d_in[8];
  const float* Wc = (const float*)d_in[9];
  const float* bc = (const float*)d_in[10];
  float* out = (float*)d_out;

  const size_t NE = (size_t)2048 * 1024;
  float* Q   = (float*)d_ws;
  float* Kf  = Q + NE;
  float* Vf  = Kf + NE;
  float* Kc  = Vf + NE;
  float* Vc  = Kc + NE;
  float* at  = Vc + NE;
  double* kn = (double*)(at + NE);
  double* tail = kn + 32768;

  const size_t fixedB = 6 * NE * 4 + 32768 * 8;
  const size_t dotPairB = (size_t)Tn * Cn * 8;   // 8 MiB per (b,h) pair
  if (ws_size < fixedB) return;

  size_t rem = ws_size - fixedB;
  double* dotp; int G;
  if      (rem >= 32 * dotPairB) { G = 32; dotp = tail; }
  else if (rem >= 16 * dotPairB) { G = 16; dotp = tail; }
  else if (rem >=  8 * dotPairB) { G = 8;  dotp = tail; }
  else if (rem >=  4 * dotPairB) { G = 4;  dotp = tail; }
  else if (rem >=  2 * dotPairB) { G = 2;  dotp = tail; }
  else { G = 2; dotp = (double*)Kf; }  // Kf+Vf dead by then (16 MiB)

  dim3 blk(256, 1, 1);

  // Fused Q/K (f64) + V (bf16) projections in one dispatch
  projQKV_k<<<dim3(16, 32, 3), blk, 0, stream>>>(
      x, Wq, Wk, Wv, bq, bk, bv, Q, Kf, Vf);

  // Fused Kc (f64, z=0,1) + Vc (bf16, z=2,3) compress
  compKV_k<<<dim3(16, 16, 4), blk, 0, stream>>>(Wc, Kf, Vf, bc, Kc, Vc);

  kn_k2<<<dim3(128), blk, 0, stream>>>(Kc, kn);

  // Dot planes (f64 SIM) + fused topk/softmax/PV
  for (int gb = 0; gb < 32; gb += G) {
    dotsim_k<<<dim3(16, 16, G), blk, 0, stream>>>(Q, Kc, dotp, gb);
    topk_attn_k<<<dim3(256 * G), blk, 0, stream>>>(dotp, kn, Vc, at, gb);
  }

  // Output projection (bf16)
  wo_k<<<dim3(16, 32, 1), blk, 0, stream>>>(at, Wo, bo, out);
}